// Round 4
// baseline (696.351 us; speedup 1.0000x reference)
//
#include <hip/hip_runtime.h>
#include <hip/hip_bf16.h>

// Rel_Transformer_Layer on MI355X gfx950.
// ROUND 4 THEORY: harness I/O is fp32 (per reference dtypes), NOT bf16.
// fp32 at the boundary, bf16 MFMA internally. d_ws unused; all scratch in d_out
// (75.5 MB): out_x region [0, 8,388,608 B) + lgx region [8,388,608, 75,497,472 B),
// lgx passthrough copied LAST.

typedef unsigned short u16;
typedef short v8s __attribute__((ext_vector_type(8)));
typedef float v4f __attribute__((ext_vector_type(4)));

#define NTOK 2048
#define DMODEL 1024
#define NHEAD 8
#define DKH 128
#define FFDIM 4096

__device__ __forceinline__ float b2f(u16 u) {
  union { unsigned int i; float f; } v; v.i = ((unsigned int)u) << 16; return v.f;
}
__device__ __forceinline__ u16 f2b(float f) {
  unsigned int x = __float_as_uint(f);
  x = x + 0x7FFFu + ((x >> 16) & 1u);   // RNE
  return (u16)(x >> 16);
}

// xb = bf16(x + in_deg_emb[in_degree] + out_deg_emb[out_degree]); all fp32 in
__global__ __launch_bounds__(256)
void prep_x(const float* __restrict__ x, const int* __restrict__ ind, const int* __restrict__ outd,
            const float* __restrict__ iw, const float* __restrict__ ow, u16* __restrict__ xb)
{
  const int n = blockIdx.x, t = threadIdx.x;
  const int a = ind[n], c = outd[n];
  const size_t o = (size_t)n * DMODEL + t * 4;
  float4 xv = *(const float4*)(x + o);
  float4 av = *(const float4*)(iw + (size_t)a * DMODEL + t * 4);
  float4 cv = *(const float4*)(ow + (size_t)c * DMODEL + t * 4);
  ushort4 ob;
  ob.x = f2b(xv.x + av.x + cv.x);
  ob.y = f2b(xv.y + av.y + cv.y);
  ob.z = f2b(xv.z + av.z + cv.z);
  ob.w = f2b(xv.w + av.w + cv.w);
  *(ushort4*)(xb + o) = ob;
}

// etw[r] = scale * sum_d rel_emb[r,d]*rel_weight[r,d]  (fp32 in)
__global__ void etw_k(const float* __restrict__ re, const float* __restrict__ rw, float* __restrict__ etw)
{
  const int r = threadIdx.x;
  if (r < 64) {
    float s = 0.f;
    for (int d = 0; d < DKH; d++) s += re[r * DKH + d] * rw[r * DKH + d];
    etw[r] = s * 0.08838834764831845f;  // 1/sqrt(128)
  }
}

// pack 6 fp32 bias vectors -> bf16: [bq 1024][bk 1024][bv 1024][bo 1024][b1 4096][b2 1024]
__global__ __launch_bounds__(256)
void pack_biases(const float* bq, const float* bk, const float* bv,
                 const float* bo, const float* b1, const float* b2, u16* __restrict__ dst)
{
  const int i = blockIdx.x * 256 + threadIdx.x;   // 10240 total
  float v;
  if      (i < 1024) v = bq[i];
  else if (i < 2048) v = bk[i - 1024];
  else if (i < 3072) v = bv[i - 2048];
  else if (i < 4096) v = bo[i - 3072];
  else if (i < 8192) v = b1[i - 4096];
  else               v = b2[i - 8192];
  dst[i] = f2b(v);
}

// bias2d[n,m] = bf16( sum_l etw[pet[n,m,l]]*paw[n,m,l] + path_len_emb[dist[n,m]] )
__global__ __launch_bounds__(256)
void bias2d_k(const int* __restrict__ pet, const float* __restrict__ paw,
              const int* __restrict__ dist, const float* __restrict__ etw,
              const float* __restrict__ plen, u16* __restrict__ out)
{
  __shared__ float se[64], sd[16];
  const int t = threadIdx.x;
  if (t < 64) se[t] = etw[t];
  if (t < 16) sd[t] = plen[t];
  __syncthreads();
  const size_t idx = (size_t)blockIdx.x * 256 + t;
  int4 p = ((const int4*)pet)[idx];
  float4 w = ((const float4*)paw)[idx];
  float s = se[p.x] * w.x + se[p.y] * w.y + se[p.z] * w.z + se[p.w] * w.w;
  s += sd[dist[idx]];
  out[idx] = f2b(s);
}

// transpose-convert: src fp32 [R][C] -> dst bf16 [C][R]; block (32,8), grid (C/32, R/32)
__global__ __launch_bounds__(256)
void tc2d(const float* __restrict__ src, u16* __restrict__ dst, int R, int C)
{
  __shared__ float tile[32][33];
  const int c0 = blockIdx.x * 32, r0 = blockIdx.y * 32;
  const int tx = threadIdx.x, ty = threadIdx.y;
#pragma unroll
  for (int j = 0; j < 32; j += 8) tile[ty + j][tx] = src[(size_t)(r0 + ty + j) * C + c0 + tx];
  __syncthreads();
#pragma unroll
  for (int j = 0; j < 32; j += 8) dst[(size_t)(c0 + ty + j) * R + r0 + tx] = f2b(tile[tx][ty + j]);
}

// bf16 transpose, z-batched: src [z][R][C] -> dst [z][C][R]; block (32,8)
__global__ __launch_bounds__(256)
void transpose2d(const u16* __restrict__ src, u16* __restrict__ dst, int R, int C)
{
  __shared__ u16 tile[32][33];
  const size_t zo = (size_t)blockIdx.z * R * C;
  const int c0 = blockIdx.x * 32, r0 = blockIdx.y * 32;
  const int tx = threadIdx.x, ty = threadIdx.y;
#pragma unroll
  for (int j = 0; j < 32; j += 8) tile[ty + j][tx] = src[zo + (size_t)(r0 + ty + j) * C + c0 + tx];
  __syncthreads();
#pragma unroll
  for (int j = 0; j < 32; j += 8) dst[zo + (size_t)(c0 + ty + j) * R + r0 + tx] = tile[tx][ty + j];
}

// row softmax in-place over bf16 scores, row length 2048
__global__ __launch_bounds__(256)
void softmax_inplace(u16* __restrict__ s)
{
  const size_t base = (size_t)blockIdx.x * 2048;
  const int t = threadIdx.x;
  v8s raw = *(const v8s*)&s[base + t * 8];
  float v[8], p[8];
  float mx = -1e30f;
#pragma unroll
  for (int i = 0; i < 8; i++) { v[i] = b2f((u16)raw[i]); mx = fmaxf(mx, v[i]); }
#pragma unroll
  for (int o = 32; o > 0; o >>= 1) mx = fmaxf(mx, __shfl_xor(mx, o, 64));
  __shared__ float sm[4], ss[4];
  if ((t & 63) == 0) sm[t >> 6] = mx;
  __syncthreads();
  mx = fmaxf(fmaxf(sm[0], sm[1]), fmaxf(sm[2], sm[3]));
  float sum = 0.f;
#pragma unroll
  for (int i = 0; i < 8; i++) { p[i] = __expf(v[i] - mx); sum += p[i]; }
#pragma unroll
  for (int o = 32; o > 0; o >>= 1) sum += __shfl_xor(sum, o, 64);
  if ((t & 63) == 0) ss[t >> 6] = sum;
  __syncthreads();
  sum = ss[0] + ss[1] + ss[2] + ss[3];
  const float r = 1.f / sum;
  v8s o8;
#pragma unroll
  for (int i = 0; i < 8; i++) o8[i] = (short)f2b(p[i] * r);
  *(v8s*)&s[base + t * 8] = o8;
}

// LN(base+add)*g+b ; base/add bf16, g/b fp32; writes outb (bf16) and/or outf (fp32)
__global__ __launch_bounds__(256)
void resid_ln(const u16* __restrict__ base, const u16* __restrict__ add,
              const float* __restrict__ g, const float* __restrict__ b,
              u16* __restrict__ outb, float* __restrict__ outf)
{
  const size_t o = (size_t)blockIdx.x * DMODEL;
  const int t = threadIdx.x;
  ushort4 x4 = *(const ushort4*)(base + o + t * 4);
  ushort4 a4 = *(const ushort4*)(add + o + t * 4);
  float v[4] = { b2f(x4.x) + b2f(a4.x), b2f(x4.y) + b2f(a4.y),
                 b2f(x4.z) + b2f(a4.z), b2f(x4.w) + b2f(a4.w) };
  float s = v[0] + v[1] + v[2] + v[3];
  float sq = v[0] * v[0] + v[1] * v[1] + v[2] * v[2] + v[3] * v[3];
#pragma unroll
  for (int off = 32; off > 0; off >>= 1) { s += __shfl_xor(s, off, 64); sq += __shfl_xor(sq, off, 64); }
  __shared__ float rs[4], rq[4];
  if ((t & 63) == 0) { rs[t >> 6] = s; rq[t >> 6] = sq; }
  __syncthreads();
  s = rs[0] + rs[1] + rs[2] + rs[3];
  sq = rq[0] + rq[1] + rq[2] + rq[3];
  const float mean = s * (1.f / DMODEL);
  const float var = sq * (1.f / DMODEL) - mean * mean;
  const float rstd = rsqrtf(var + 1e-5f);
  float4 gv = ((const float4*)g)[t];
  float4 bv = ((const float4*)b)[t];
  float y[4] = { (v[0] - mean) * rstd * gv.x + bv.x, (v[1] - mean) * rstd * gv.y + bv.y,
                 (v[2] - mean) * rstd * gv.z + bv.z, (v[3] - mean) * rstd * gv.w + bv.w };
  if (outb) {
    ushort4 ob; ob.x = f2b(y[0]); ob.y = f2b(y[1]); ob.z = f2b(y[2]); ob.w = f2b(y[3]);
    *(ushort4*)(outb + o + t * 4) = ob;
  }
  if (outf) ((float4*)(outf + o))[t] = make_float4(y[0], y[1], y[2], y[3]);
}

// ---------------- MFMA GEMM: C = A[M,K] * Bt[N,K]^T (+ epilogue), bf16 in/out ----------------
#define EPI_BIAS  0   // + bias[col]
#define EPI_SCORE 1   // *scale + bias2d[row*Nc+col]
#define EPI_PLAIN 2   // plain

template<int EPI, bool RELU>
__global__ __launch_bounds__(256)
void gemm_bt(const u16* __restrict__ A, const u16* __restrict__ Bt,
             const u16* __restrict__ bias, const u16* __restrict__ bias2d,
             u16* __restrict__ Cb,
             int M, int Nc, int K, int lda, int ldb, int ldc,
             long zA, long zB, long zC, long zBias, float scale)
{
  __shared__ u16 As[128 * 40];
  __shared__ u16 Bs[128 * 40];
  const int t = threadIdx.x;
  const int w = t >> 6, l = t & 63, lo = l & 15, hi = l >> 4;
  const int wm = (w >> 1) * 64, wn = (w & 1) * 64;
  const int row0 = blockIdx.x * 128, col0 = blockIdx.y * 128;
  A += (size_t)blockIdx.z * zA;
  Bt += (size_t)blockIdx.z * zB;
  const size_t coff = (size_t)blockIdx.z * zC;

  v4f acc[4][4];
#pragma unroll
  for (int i = 0; i < 4; i++)
#pragma unroll
    for (int j = 0; j < 4; j++) acc[i][j] = (v4f){0.f, 0.f, 0.f, 0.f};

  const int r0 = t >> 2, q0 = (t & 3) * 8;
  for (int k0 = 0; k0 < K; k0 += 32) {
    *(v8s*)&As[r0 * 40 + q0]        = *(const v8s*)&A[(size_t)(row0 + r0) * lda + k0 + q0];
    *(v8s*)&As[(r0 + 64) * 40 + q0] = *(const v8s*)&A[(size_t)(row0 + r0 + 64) * lda + k0 + q0];
    *(v8s*)&Bs[r0 * 40 + q0]        = *(const v8s*)&Bt[(size_t)(col0 + r0) * ldb + k0 + q0];
    *(v8s*)&Bs[(r0 + 64) * 40 + q0] = *(const v8s*)&Bt[(size_t)(col0 + r0 + 64) * ldb + k0 + q0];
    __syncthreads();
    v8s af[4], bfr[4];
#pragma unroll
    for (int i = 0; i < 4; i++) af[i] = *(const v8s*)&As[(wm + i * 16 + lo) * 40 + hi * 8];
#pragma unroll
    for (int j = 0; j < 4; j++) bfr[j] = *(const v8s*)&Bs[(wn + j * 16 + lo) * 40 + hi * 8];
#pragma unroll
    for (int i = 0; i < 4; i++)
#pragma unroll
      for (int j = 0; j < 4; j++)
        acc[i][j] = __builtin_amdgcn_mfma_f32_16x16x32_bf16(af[i], bfr[j], acc[i][j], 0, 0, 0);
    __syncthreads();
  }

  // C/D layout (m89-verified): col = lane&15, row = (lane>>4)*4 + reg
#pragma unroll
  for (int i = 0; i < 4; i++) {
#pragma unroll
    for (int j = 0; j < 4; j++) {
#pragma unroll
      for (int r = 0; r < 4; r++) {
        const int row = row0 + wm + i * 16 + hi * 4 + r;
        const int col = col0 + wn + j * 16 + lo;
        float v = acc[i][j][r];
        if (EPI == EPI_BIAS) v += b2f(bias[(size_t)blockIdx.z * zBias + col]);
        if (EPI == EPI_SCORE) v = v * scale + b2f(bias2d[(size_t)row * Nc + col]);
        if (RELU) v = fmaxf(v, 0.f);
        Cb[coff + (size_t)row * ldc + col] = f2b(v);
      }
    }
  }
}

// ---------------- launch ----------------

extern "C" void kernel_launch(void* const* d_in, const int* in_sizes, int n_in,
                              void* d_out, int out_size, void* d_ws, size_t ws_size,
                              hipStream_t stream)
{
  const float* x    = (const float*)d_in[0];
  const float* lgx  = (const float*)d_in[1];
  const int*   ind  = (const int*)d_in[2];
  const int*   outd = (const int*)d_in[3];
  const int*   dist = (const int*)d_in[4];
  const int*   pet  = (const int*)d_in[5];
  const float* paw  = (const float*)d_in[6];
  const float* rele = (const float*)d_in[7];
  const float* relw = (const float*)d_in[8];
  const float* idegw = (const float*)d_in[9];
  const float* odegw = (const float*)d_in[10];
  const float* plen = (const float*)d_in[11];
  const float* Wq = (const float*)d_in[12]; const float* bq = (const float*)d_in[13];
  const float* Wk = (const float*)d_in[14]; const float* bk = (const float*)d_in[15];
  const float* Wv = (const float*)d_in[16]; const float* bv = (const float*)d_in[17];
  const float* Wo = (const float*)d_in[18]; const float* bo = (const float*)d_in[19];
  const float* ln1g = (const float*)d_in[20]; const float* ln1b = (const float*)d_in[21];
  const float* W1 = (const float*)d_in[22]; const float* b1 = (const float*)d_in[23];
  const float* W2 = (const float*)d_in[24]; const float* b2 = (const float*)d_in[25];
  const float* ln2g = (const float*)d_in[26]; const float* ln2b = (const float*)d_in[27];
  float* O = (float*)d_out;          // 18,874,368 fp32 elems = 75,497,472 B
  char*  B = (char*)d_out;

  // ---- byte-offset map inside d_out (d_ws UNUSED) ----
  u16*   WT     = (u16*)(B + 0);            // 2 MB: per-weight T slot (QKV loop unused; WoT here)
  float* etw    = (float*)(B + 2097152);    // 256 B
  u16*   biases = (u16*)(B + 2097408);      // 20,480 B: [bq|bk|bv|bo|b1|b2] bf16
  u16*   xb     = (u16*)(B + 8388608);      // 4 MB
  u16*   bias2d = (u16*)(B + 12582912);     // 8 MB bf16 [2048][2048]
  u16*   q      = (u16*)(B + 20971520);     // 4 MB  (obuf overwrites per dead head)
  u16*   k      = (u16*)(B + 25165824);     // 4 MB
  u16*   v      = (u16*)(B + 29360128);     // 4 MB
  u16*   kT     = (u16*)(B + 33554432);     // 4 MB [8][2048][128]
  u16*   vT     = (u16*)(B + 37748736);     // 4 MB [8][128][2048]
  u16*   scores = (u16*)(B + 41943040);     // 32 MB: 4 heads/batch
  u16*   WTqkv  = (u16*)(B + 41943040);     // 6 MB transient (dead before scores)
  // FFN phase (attention buffers dead):
  u16*   obuf = q;
  u16*   WoT  = WT;
  u16*   W1T  = kT;                          // 8 MB spanning kT+vT slots
  u16*   W2T  = kT;
  u16*   f1   = (u16*)(B + 41943040);        // 16 MB over dead scores
  u16*   f2   = (u16*)(B + 58720256);        // 4 MB
  u16*   o2   = (u16*)(B + 62914560);        // 4 MB
  u16*   hb   = (u16*)(B + 67108864);        // 4 MB

  const dim3 tb(32, 8);

  prep_x<<<NTOK, 256, 0, stream>>>(x, ind, outd, idegw, odegw, xb);
  etw_k<<<1, 64, 0, stream>>>(rele, relw, etw);
  pack_biases<<<40, 256, 0, stream>>>(bq, bk, bv, bo, b1, b2, biases);
  bias2d_k<<<(NTOK * NTOK) / 256, 256, 0, stream>>>(pet, paw, dist, etw, plen, bias2d);

  // QKV: Wq/Wk/Wv -> bf16 transposed, then one z=3 batched GEMM
  tc2d<<<dim3(32, 32), tb, 0, stream>>>(Wq, WTqkv, 1024, 1024);
  tc2d<<<dim3(32, 32), tb, 0, stream>>>(Wk, WTqkv + 1048576, 1024, 1024);
  tc2d<<<dim3(32, 32), tb, 0, stream>>>(Wv, WTqkv + 2097152, 1024, 1024);
  gemm_bt<EPI_BIAS, false><<<dim3(16, 8, 3), 256, 0, stream>>>(
      xb, WTqkv, biases, nullptr, q,
      2048, 1024, 1024, 1024, 1024, 1024,
      0L, 1048576L, 2097152L, 1024L, 0.f);   // writes q,k,v (zC=2M elems apart)

  // k flat [8][128][2048] -> kT [8][2048][128]; v flat [8][2048][128] -> vT [8][128][2048]
  transpose2d<<<dim3(64, 4, 8), tb, 0, stream>>>(k, kT, 128, 2048);
  transpose2d<<<dim3(4, 64, 8), tb, 0, stream>>>(v, vT, 2048, 128);

  // attention in 2 batches of 4 heads
  for (int h0 = 0; h0 < 8; h0 += 4) {
    const size_t ho = (size_t)h0 * 262144;
    gemm_bt<EPI_SCORE, false><<<dim3(16, 16, 4), 256, 0, stream>>>(
        q + ho, kT + ho, nullptr, bias2d, scores,
        2048, 2048, 128, 128, 128, 2048,
        262144L, 262144L, 4194304L, 0L, 0.08838834764831845f);
    softmax_inplace<<<4 * NTOK, 256, 0, stream>>>(scores);
    gemm_bt<EPI_PLAIN, false><<<dim3(16, 1, 4), 256, 0, stream>>>(
        scores, vT + ho, nullptr, nullptr, obuf + ho,
        2048, 128, 2048, 2048, 2048, 128,
        4194304L, 262144L, 262144L, 0L, 0.f);
  }

  // o2 = obuf @ Wo + bo
  tc2d<<<dim3(32, 32), tb, 0, stream>>>(Wo, WoT, 1024, 1024);
  gemm_bt<EPI_BIAS, false><<<dim3(16, 8, 1), 256, 0, stream>>>(
      obuf, WoT, biases + 3072, nullptr, o2,
      2048, 1024, 1024, 1024, 1024, 1024, 0L, 0L, 0L, 0L, 0.f);

  // h = LN(xb + o2)
  resid_ln<<<NTOK, 256, 0, stream>>>(xb, o2, ln1g, ln1b, hb, nullptr);

  // f1 = relu(h @ W1 + b1)
  tc2d<<<dim3(128, 32), tb, 0, stream>>>(W1, W1T, 1024, 4096);
  gemm_bt<EPI_BIAS, true><<<dim3(16, 32, 1), 256, 0, stream>>>(
      hb, W1T, biases + 4096, nullptr, f1,
      2048, 4096, 1024, 1024, 1024, 4096, 0L, 0L, 0L, 0L, 0.f);

  // f2 = f1 @ W2 + b2
  tc2d<<<dim3(32, 128), tb, 0, stream>>>(W2, W2T, 4096, 1024);
  gemm_bt<EPI_BIAS, false><<<dim3(16, 8, 1), 256, 0, stream>>>(
      f1, W2T, biases + 8192, nullptr, f2,
      2048, 1024, 4096, 4096, 4096, 1024, 0L, 0L, 0L, 0L, 0.f);

  // out_x = LN(hb + f2) -> fp32 into d_out[0..2M)
  resid_ln<<<NTOK, 256, 0, stream>>>(hb, f2, ln2g, ln2b, nullptr, O);

  // lgx passthrough LAST (fp32, 64 MB; its region doubled as scratch above)
  hipMemcpyAsync(B + 8388608, lgx, 67108864ull, hipMemcpyDeviceToDevice, stream);
}